// Round 1
// baseline (609.158 us; speedup 1.0000x reference)
//
#include <hip/hip_runtime.h>

#define WF 257
#define LAM 0.01f

__device__ __forceinline__ int drev(int x){ return ((x&7)<<6) | (x&56) | ((x>>6)&7); }
#define LPAD(i) ((i) + ((i)>>3))

__device__ __forceinline__ float2 cmul(float2 a, float2 b){
    return make_float2(a.x*b.x - a.y*b.y, a.x*b.y + a.y*b.x);
}
__device__ __forceinline__ float2 cadd(float2 a, float2 b){ return make_float2(a.x+b.x, a.y+b.y); }
__device__ __forceinline__ float2 csub(float2 a, float2 b){ return make_float2(a.x-b.x, a.y-b.y); }

__device__ __forceinline__ void fill_tw(float2* tw, int tid, int nthr){
    for (int t = tid; t < 512; t += nthr) {
        float a = (float)t * (-6.2831853071795864769f/512.0f);
        float s, c;
        sincosf(a, &s, &c);
        tw[t] = make_float2(c, s);
    }
}

template<bool INV>
__device__ __forceinline__ void dft8(float2 v[8]) {
    const float R = 0.70710678118654752f;
    float2 y0=v[0], y1=v[4], y2=v[2], y3=v[6], y4=v[1], y5=v[5], y6=v[3], y7=v[7];
    float2 t;
    // stage 1
    t=y1; y1=csub(y0,t); y0=cadd(y0,t);
    t=y3; y3=csub(y2,t); y2=cadd(y2,t);
    t=y5; y5=csub(y4,t); y4=cadd(y4,t);
    t=y7; y7=csub(y6,t); y6=cadd(y6,t);
    // stage 2
    t=y2; y2=csub(y0,t); y0=cadd(y0,t);
    t = INV ? make_float2(-y3.y, y3.x) : make_float2(y3.y, -y3.x);
    y3=csub(y1,t); y1=cadd(y1,t);
    t=y6; y6=csub(y4,t); y4=cadd(y4,t);
    t = INV ? make_float2(-y7.y, y7.x) : make_float2(y7.y, -y7.x);
    y7=csub(y5,t); y5=cadd(y5,t);
    // stage 3
    t=y4; y4=csub(y0,t); y0=cadd(y0,t);
    { float2 w8 = INV ? make_float2(R, R) : make_float2(R,-R);
      t=cmul(y5,w8); y5=csub(y1,t); y1=cadd(y1,t); }
    t = INV ? make_float2(-y6.y, y6.x) : make_float2(y6.y, -y6.x);
    y6=csub(y2,t); y2=cadd(y2,t);
    { float2 w8 = INV ? make_float2(-R, R) : make_float2(-R,-R);
      t=cmul(y7,w8); y7=csub(y3,t); y3=cadd(y3,t); }
    v[0]=y0; v[1]=y1; v[2]=y2; v[3]=y3; v[4]=y4; v[5]=y5; v[6]=y6; v[7]=y7;
}

// 512-point FFT, radix-8 (3 stages), digit-reversed input, natural output.
// d: NROWS rows of 576 float2 (LPAD'd 512). One butterfly-octet per thread per stage.
template<int NROWS, int NTHREADS, bool INV>
__device__ __forceinline__ void fft512_r8(float2* d, const float2* tw, int tid)
{
    #pragma unroll
    for (int s = 0; s < 3; ++s) {
        const int hlen = 1 << (3*s);
        const int T = 64 >> (3*s);
        __syncthreads();
        #pragma unroll
        for (int rep = 0; rep < (NROWS*64)/NTHREADS; ++rep) {
            int slot = rep*NTHREADS + tid;
            int row = slot >> 6;
            int j = slot & 63;
            int p = j & (hlen-1);
            int base = row*576;
            int i0 = (j - p)*8 + p;
            float2 v[8];
            #pragma unroll
            for (int q = 0; q < 8; ++q) {
                int idx = i0 + q*hlen;
                float2 a = d[base + LPAD(idx)];
                if (s > 0 && q > 0) {
                    float2 wv = tw[(p*q*T) & 511];
                    if (INV) wv.y = -wv.y;
                    a = cmul(a, wv);
                }
                v[q] = a;
            }
            dft8<INV>(v);
            #pragma unroll
            for (int q = 0; q < 8; ++q)
                d[base + LPAD(i0 + q*hlen)] = v[q];
        }
    }
    __syncthreads();
}

// ---------------- conv 3x3 + bias ----------------
__global__ void k_transw(const float* __restrict__ w, float* __restrict__ wt){
    int i = blockIdx.x*256 + threadIdx.x;
    if (i < 9216) {
        int ci = i / 288, r = i % 288, tap = r / 32, co = r % 32;
        wt[i] = w[(co*32+ci)*9 + tap];
    }
}

__global__ __launch_bounds__(256) void k_conv(
    const float* __restrict__ x, const float4* __restrict__ wt4,
    const float* __restrict__ bias, float* __restrict__ out)
{
    __shared__ float it[8*612];   // 8 ci x 34 x 18
    const int tid = threadIdx.x;
    const int bx = blockIdx.x, by = blockIdx.y, b = blockIdx.z;
    const int tx = tid & 15, ty = tid >> 4;
    const int gx0 = bx*16 - 1, gy0 = by*32 - 1;
    float acc0[32], acc1[32];
    #pragma unroll
    for (int q = 0; q < 32; ++q){ acc0[q]=0.f; acc1[q]=0.f; }
    for (int ch = 0; ch < 4; ++ch) {
        if (ch) __syncthreads();
        for (int i = tid; i < 8*612; i += 256) {
            int cl = i / 612, r2 = i % 612, iy = r2 / 18, ix = r2 % 18;
            int gy = gy0 + iy, gx = gx0 + ix;
            float v = 0.f;
            if ((unsigned)gy < 512u && (unsigned)gx < 512u)
                v = x[((b*32 + ch*8 + cl)*512 + gy)*512 + gx];
            it[i] = v;
        }
        __syncthreads();
        for (int cl = 0; cl < 8; ++cl) {
            const float* itc = &it[cl*612];
            const int ci = ch*8 + cl;
            #pragma unroll
            for (int tap = 0; tap < 9; ++tap) {
                const int dy = tap/3, dx = tap - dy*3;
                float xv0 = itc[(ty+dy)*18 + tx+dx];
                float xv1 = itc[(ty+16+dy)*18 + tx+dx];
                const float4* wrow = &wt4[(ci*9+tap)*8];
                #pragma unroll
                for (int q8 = 0; q8 < 8; ++q8) {
                    float4 wv = wrow[q8];
                    acc0[q8*4+0] = fmaf(xv0, wv.x, acc0[q8*4+0]);
                    acc0[q8*4+1] = fmaf(xv0, wv.y, acc0[q8*4+1]);
                    acc0[q8*4+2] = fmaf(xv0, wv.z, acc0[q8*4+2]);
                    acc0[q8*4+3] = fmaf(xv0, wv.w, acc0[q8*4+3]);
                    acc1[q8*4+0] = fmaf(xv1, wv.x, acc1[q8*4+0]);
                    acc1[q8*4+1] = fmaf(xv1, wv.y, acc1[q8*4+1]);
                    acc1[q8*4+2] = fmaf(xv1, wv.z, acc1[q8*4+2]);
                    acc1[q8*4+3] = fmaf(xv1, wv.w, acc1[q8*4+3]);
                }
            }
        }
    }
    const int gx = bx*16 + tx, gyA = by*32 + ty, gyB = gyA + 16;
    #pragma unroll
    for (int co = 0; co < 32; ++co) {
        float bv = bias[co];
        out[((b*32+co)*512 + gyA)*512 + gx] = acc0[co] + bv;
        out[((b*32+co)*512 + gyB)*512 + gx] = acc1[co] + bv;
    }
}

// ---------------- per-channel sum/sumsq ----------------
__global__ __launch_bounds__(256) void k_stats(const float* __restrict__ src, float* __restrict__ stats)
{
    __shared__ float2 red[4];
    const int tid = threadIdx.x;
    const int bc = blockIdx.y, c = bc & 31;
    const float4* p = (const float4*)(src) + (size_t)bc*65536 + (size_t)blockIdx.x*8192;
    float ls = 0.f, lsq = 0.f;
    for (int i = tid; i < 8192; i += 256) {
        float4 v = p[i];
        ls  += (v.x + v.y) + (v.z + v.w);
        lsq += (v.x*v.x + v.y*v.y) + (v.z*v.z + v.w*v.w);
    }
    #pragma unroll
    for (int off = 32; off; off >>= 1) { ls += __shfl_down(ls, off, 64); lsq += __shfl_down(lsq, off, 64); }
    if ((tid & 63) == 0) red[tid >> 6] = make_float2(ls, lsq);
    __syncthreads();
    if (tid == 0) {
        float a = 0.f, bb = 0.f;
        #pragma unroll
        for (int i = 0; i < 4; ++i){ a += red[i].x; bb += red[i].y; }
        atomicAdd(&stats[c], a);
        atomicAdd(&stats[32+c], bb);
    }
}

__global__ void k_finalize(const float* __restrict__ stats, const float* __restrict__ g,
                           const float* __restrict__ bta, float* __restrict__ bnp)
{
    int c = threadIdx.x;
    if (c < 32) {
        const float inv_n = 1.f/1048576.f;
        float mean = stats[c] * inv_n;
        float var  = stats[32+c] * inv_n - mean*mean;
        float s = g[c] * rsqrtf(var + 1e-5f);
        bnp[c] = s;
        bnp[32+c] = bta[c] - mean*s;
    }
}

// ---------------- row rfft (W axis), fused BN1+ReLU, transposed write ----------------
__global__ __launch_bounds__(512) void k_rowfft_fwd(
    const float* __restrict__ cvo, const float* __restrict__ bnp,
    float2* __restrict__ spec)
{
    __shared__ float2 tw[512];
    __shared__ float2 d[8*576];
    const int tid = threadIdx.x;
    const int h0 = blockIdx.x * 8;
    const int bc = blockIdx.y;
    const int c = bc & 31;
    fill_tw(tw, tid, 512);
    const float s1 = bnp[c], t1 = bnp[32+c];
    #pragma unroll
    for (int r = 0; r < 8; ++r) {
        float v = cvo[(bc*512 + h0 + r)*512 + tid];
        float y = fmaxf(fmaf(v, s1, t1), 0.f);
        d[r*576 + LPAD(drev(tid))] = make_float2(y, 0.f);
    }
    fft512_r8<8,512,false>(d, tw, tid);
    for (int i = tid; i < 8*WF; i += 512) {
        int ho = i & 7, w = i >> 3;
        spec[(bc*WF + w)*512 + h0 + ho] = d[ho*576 + LPAD(w)];
    }
}

// ---------------- col FFT (H) + MLP/gate + inverse col FFT, in place ----------------
__global__ __launch_bounds__(256) void k_colfft(float2* __restrict__ spec,
    const float* __restrict__ w1, const float* __restrict__ b1,
    const float* __restrict__ w2, const float* __restrict__ b2)
{
    __shared__ float2 tw[512];
    __shared__ float2 d[4*576];
    __shared__ float wl[80];
    const int tid = threadIdx.x;
    const int w = blockIdx.x;
    const int k = blockIdx.y;
    const int b = blockIdx.z;
    fill_tw(tw, tid, 256);
    if (tid < 16) {
        wl[tid]      = w1[k*16 + tid];
        wl[16 + tid] = w1[128 + k*16 + tid];
        wl[32 + tid] = w2[k*16 + tid];
        wl[48 + tid] = w2[128 + k*16 + tid];
    } else if (tid < 20) {
        int o = tid - 16;
        wl[64 + o] = b1[k*4 + o];
        wl[68 + o] = b1[32 + k*4 + o];
        wl[72 + o] = b2[k*4 + o];
        wl[76 + o] = b2[32 + k*4 + o];
    }
    const int base0 = ((b*32 + k*4)*WF + w) * 512;
    #pragma unroll
    for (int cc = 0; cc < 4; ++cc) {
        float4 v = ((const float4*)(spec + base0 + cc*(WF*512)))[tid];
        d[cc*576 + LPAD(drev(2*tid))]   = make_float2(v.x, v.y);
        d[cc*576 + LPAD(drev(2*tid+1))] = make_float2(v.z, v.w);
    }
    fft512_r8<4,256,false>(d, tw, tid);
    float zr[2][4], zi[2][4];
    #pragma unroll
    for (int rep = 0; rep < 2; ++rep) {
        const int ph = LPAD(rep*256 + tid);
        float xr[4], xi[4];
        #pragma unroll
        for (int i = 0; i < 4; ++i) {
            float2 v = d[i*576 + ph];
            xr[i] = v.x * (1.f/512.f);
            xi[i] = v.y * (1.f/512.f);
        }
        float o1r[4], o1i[4];
        #pragma unroll
        for (int o = 0; o < 4; ++o) {
            float sr = wl[64+o], si = wl[68+o];
            #pragma unroll
            for (int i = 0; i < 4; ++i) {
                float wr = wl[i*4+o], wi = wl[16 + i*4+o];
                sr += xr[i]*wr - xi[i]*wi;
                si += xi[i]*wr + xr[i]*wi;
            }
            o1r[o] = fmaxf(sr, 0.f);
            o1i[o] = fmaxf(si, 0.f);
        }
        #pragma unroll
        for (int o = 0; o < 4; ++o) {
            float sr = wl[72+o], si = wl[76+o];
            #pragma unroll
            for (int i = 0; i < 4; ++i) {
                float wr = wl[32 + i*4+o], wi = wl[48 + i*4+o];
                sr += o1r[i]*wr - o1i[i]*wi;
                si += o1i[i]*wr + o1r[i]*wi;
            }
            sr = (sr > LAM) ? sr - LAM : ((sr < -LAM) ? sr + LAM : 0.f);
            si = (si > LAM) ? si - LAM : ((si < -LAM) ? si + LAM : 0.f);
            zr[rep][o] = sr*xr[o] - si*xi[o];
            zi[rep][o] = sr*xi[o] + si*xr[o];
        }
    }
    __syncthreads();
    #pragma unroll
    for (int rep = 0; rep < 2; ++rep) {
        const int hb = LPAD(drev(rep*256 + tid));
        #pragma unroll
        for (int cc = 0; cc < 4; ++cc)
            d[cc*576 + hb] = make_float2(zr[rep][cc], zi[rep][cc]);
    }
    fft512_r8<4,256,true>(d, tw, tid);
    #pragma unroll
    for (int cc = 0; cc < 4; ++cc) {
        float2 a  = d[cc*576 + LPAD(2*tid)];
        float2 b2v = d[cc*576 + LPAD(2*tid+1)];
        ((float4*)(spec + base0 + cc*(WF*512)))[tid] = make_float4(a.x, a.y, b2v.x, b2v.y);
    }
}

// ---------------- row irfft (W axis) + residual + BN2 stats ----------------
__global__ __launch_bounds__(512) void k_rowfft_inv(
    const float2* __restrict__ spec, const float* __restrict__ cvo,
    const float* __restrict__ bnp, float* __restrict__ fo, float* __restrict__ stats2)
{
    __shared__ float2 tw[512];
    __shared__ float2 d[8*576];
    __shared__ float2 red[8];
    const int tid = threadIdx.x;
    const int h0 = blockIdx.x * 8;
    const int bc = blockIdx.y;
    const int c = bc & 31;
    fill_tw(tw, tid, 512);
    for (int i = tid; i < 8*WF; i += 512) {
        int ho = i & 7, w = i >> 3;
        float2 v = spec[(bc*WF + w)*512 + h0 + ho];
        d[ho*576 + LPAD(drev(w))] = v;
        if ((unsigned)(w - 1) < 255u)
            d[ho*576 + LPAD(drev(512 - w))] = make_float2(v.x, -v.y);
    }
    fft512_r8<8,512,true>(d, tw, tid);
    const float s1 = bnp[c], t1 = bnp[32+c];
    float ls = 0.f, lsq = 0.f;
    #pragma unroll
    for (int r = 0; r < 8; ++r) {
        int gi = (bc*512 + h0 + r)*512 + tid;
        float cv = cvo[gi];
        float yv = fmaxf(fmaf(cv, s1, t1), 0.f);
        float val = fmaf(d[r*576 + LPAD(tid)].x, (1.f/512.f), yv);
        fo[gi] = val;
        ls += val; lsq += val*val;
    }
    #pragma unroll
    for (int off = 32; off; off >>= 1) { ls += __shfl_down(ls, off, 64); lsq += __shfl_down(lsq, off, 64); }
    if ((tid & 63) == 0) red[tid >> 6] = make_float2(ls, lsq);
    __syncthreads();
    if (tid == 0) {
        float a = 0.f, bb = 0.f;
        #pragma unroll
        for (int i = 0; i < 8; ++i){ a += red[i].x; bb += red[i].y; }
        atomicAdd(&stats2[c], a);
        atomicAdd(&stats2[32+c], bb);
    }
}

// ---------------- final: out = relu(y + bn2(fo)) ----------------
__global__ __launch_bounds__(256) void k_final(const float* __restrict__ cvo,
    const float* __restrict__ bnp1, const float* __restrict__ bnp2, float* __restrict__ out)
{
    const int n4 = 8388608;
    for (int i = blockIdx.x*256 + threadIdx.x; i < n4; i += gridDim.x*256) {
        int c = (i >> 16) & 31;
        float s1 = bnp1[c], t1 = bnp1[32+c], s2 = bnp2[c], t2 = bnp2[32+c];
        float4 cv = ((const float4*)cvo)[i];
        float4 fv = ((float4*)out)[i];
        float4 r;
        r.x = fmaxf(fmaxf(fmaf(cv.x,s1,t1),0.f) + fmaf(fv.x,s2,t2), 0.f);
        r.y = fmaxf(fmaxf(fmaf(cv.y,s1,t1),0.f) + fmaf(fv.y,s2,t2), 0.f);
        r.z = fmaxf(fmaxf(fmaf(cv.z,s1,t1),0.f) + fmaf(fv.z,s2,t2), 0.f);
        r.w = fmaxf(fmaxf(fmaf(cv.w,s1,t1),0.f) + fmaf(fv.w,s2,t2), 0.f);
        ((float4*)out)[i] = r;
    }
}

extern "C" void kernel_launch(void* const* d_in, const int* in_sizes, int n_in,
                              void* d_out, int out_size, void* d_ws, size_t ws_size,
                              hipStream_t stream)
{
    const float* x      = (const float*)d_in[0];
    const float* conv_w = (const float*)d_in[1];
    const float* conv_b = (const float*)d_in[2];
    const float* bn1g   = (const float*)d_in[3];
    const float* bn1b   = (const float*)d_in[4];
    const float* w1     = (const float*)d_in[5];
    const float* b1     = (const float*)d_in[6];
    const float* w2     = (const float*)d_in[7];
    const float* b2     = (const float*)d_in[8];
    const float* bn2g   = (const float*)d_in[9];
    const float* bn2b   = (const float*)d_in[10];
    float* out = (float*)d_out;

    char* ws = (char*)d_ws;
    float2* spec  = (float2*)ws;                                   // 134,742,016 B
    float*  cvo   = (float*)(ws + 134742016);                      // 134,217,728 B
    float*  wt    = (float*)(ws + 134742016 + 134217728);          // 36,864 B
    float*  stats = (float*)(ws + 134742016 + 134217728 + 36864);  // 256 floats
    float* stats1 = stats;
    float* stats2 = stats + 64;
    float* bnp1   = stats + 128;
    float* bnp2   = stats + 192;

    hipMemsetAsync(stats, 0, 128*sizeof(float), stream);
    k_transw<<<36, 256, 0, stream>>>(conv_w, wt);
    k_conv<<<dim3(32,16,4), 256, 0, stream>>>(x, (const float4*)wt, conv_b, cvo);
    k_stats<<<dim3(8,128), 256, 0, stream>>>(cvo, stats1);
    k_finalize<<<1, 64, 0, stream>>>(stats1, bn1g, bn1b, bnp1);
    k_rowfft_fwd<<<dim3(64,128), 512, 0, stream>>>(cvo, bnp1, spec);
    k_colfft<<<dim3(257,8,4), 256, 0, stream>>>(spec, w1, b1, w2, b2);
    k_rowfft_inv<<<dim3(64,128), 512, 0, stream>>>(spec, cvo, bnp1, out, stats2);
    k_finalize<<<1, 64, 0, stream>>>(stats2, bn2g, bn2b, bnp2);
    k_final<<<2048, 256, 0, stream>>>(cvo, bnp1, bnp2, out);
}

// Round 2
// 472.582 us; speedup vs baseline: 1.2890x; 1.2890x over previous
//
#include <hip/hip_runtime.h>

#define WF 257
#define LAM 0.01f

typedef __attribute__((ext_vector_type(8))) short short8;
typedef __attribute__((ext_vector_type(4))) float f32x4;

__device__ __forceinline__ ushort f2bf(float f){
    unsigned u = __float_as_uint(f);
    unsigned r = (u + 0x7fffu + ((u >> 16) & 1u)) >> 16;
    return (ushort)r;
}

__device__ __forceinline__ int drev(int x){ return ((x&7)<<6) | (x&56) | ((x>>6)&7); }
#define LPAD(i) ((i) + ((i)>>3))

__device__ __forceinline__ float2 cmul(float2 a, float2 b){
    return make_float2(a.x*b.x - a.y*b.y, a.x*b.y + a.y*b.x);
}
__device__ __forceinline__ float2 cadd(float2 a, float2 b){ return make_float2(a.x+b.x, a.y+b.y); }
__device__ __forceinline__ float2 csub(float2 a, float2 b){ return make_float2(a.x-b.x, a.y-b.y); }

__device__ __forceinline__ void fill_tw(float2* tw, int tid, int nthr){
    for (int t = tid; t < 512; t += nthr) {
        float a = (float)t * (-6.2831853071795864769f/512.0f);
        float s, c;
        sincosf(a, &s, &c);
        tw[t] = make_float2(c, s);
    }
}

template<bool INV>
__device__ __forceinline__ void dft8(float2 v[8]) {
    const float R = 0.70710678118654752f;
    float2 y0=v[0], y1=v[4], y2=v[2], y3=v[6], y4=v[1], y5=v[5], y6=v[3], y7=v[7];
    float2 t;
    t=y1; y1=csub(y0,t); y0=cadd(y0,t);
    t=y3; y3=csub(y2,t); y2=cadd(y2,t);
    t=y5; y5=csub(y4,t); y4=cadd(y4,t);
    t=y7; y7=csub(y6,t); y6=cadd(y6,t);
    t=y2; y2=csub(y0,t); y0=cadd(y0,t);
    t = INV ? make_float2(-y3.y, y3.x) : make_float2(y3.y, -y3.x);
    y3=csub(y1,t); y1=cadd(y1,t);
    t=y6; y6=csub(y4,t); y4=cadd(y4,t);
    t = INV ? make_float2(-y7.y, y7.x) : make_float2(y7.y, -y7.x);
    y7=csub(y5,t); y5=cadd(y5,t);
    t=y4; y4=csub(y0,t); y0=cadd(y0,t);
    { float2 w8 = INV ? make_float2(R, R) : make_float2(R,-R);
      t=cmul(y5,w8); y5=csub(y1,t); y1=cadd(y1,t); }
    t = INV ? make_float2(-y6.y, y6.x) : make_float2(y6.y, -y6.x);
    y6=csub(y2,t); y2=cadd(y2,t);
    { float2 w8 = INV ? make_float2(-R, R) : make_float2(-R,-R);
      t=cmul(y7,w8); y7=csub(y3,t); y3=cadd(y3,t); }
    v[0]=y0; v[1]=y1; v[2]=y2; v[3]=y3; v[4]=y4; v[5]=y5; v[6]=y6; v[7]=y7;
}

template<int NROWS, int NTHREADS, bool INV>
__device__ __forceinline__ void fft512_r8(float2* d, const float2* tw, int tid)
{
    #pragma unroll
    for (int s = 0; s < 3; ++s) {
        const int hlen = 1 << (3*s);
        const int T = 64 >> (3*s);
        __syncthreads();
        #pragma unroll
        for (int rep = 0; rep < (NROWS*64)/NTHREADS; ++rep) {
            int slot = rep*NTHREADS + tid;
            int row = slot >> 6;
            int j = slot & 63;
            int p = j & (hlen-1);
            int base = row*576;
            int i0 = (j - p)*8 + p;
            float2 v[8];
            #pragma unroll
            for (int q = 0; q < 8; ++q) {
                int idx = i0 + q*hlen;
                float2 a = d[base + LPAD(idx)];
                if (s > 0 && q > 0) {
                    float2 wv = tw[(p*q*T) & 511];
                    if (INV) wv.y = -wv.y;
                    a = cmul(a, wv);
                }
                v[q] = a;
            }
            dft8<INV>(v);
            #pragma unroll
            for (int q = 0; q < 8; ++q)
                d[base + LPAD(i0 + q*hlen)] = v[q];
        }
    }
    __syncthreads();
}

// ---------------- weight prep: bf16 MFMA A-fragments ----------------
// wtp[((tap*2+m)*64 + lane)*8 + j] = w[co=m*16+(lane&15)][ci=(lane>>4)*8+j][tap]
__global__ void k_wprep(const float* __restrict__ w, ushort* __restrict__ wtp){
    int i = blockIdx.x*256 + threadIdx.x;
    if (i < 9216) {
        int j = i & 7, l = (i>>3) & 63, m = (i>>9) & 1, tap = i >> 10;
        int co = m*16 + (l & 15), ci = ((l>>4)&3)*8 + j;
        wtp[i] = f2bf(w[(co*32 + ci)*9 + tap]);
    }
}

// ---------------- NCHW fp32 -> NHWC bf16 transpose ----------------
__global__ __launch_bounds__(256) void k_transpose(const float* __restrict__ x, ushort* __restrict__ xt){
    __shared__ ushort tl[64][36];
    const int tid = threadIdx.x;
    const int w0 = blockIdx.x*64, h = blockIdx.y, b = blockIdx.z;
    #pragma unroll
    for (int it = 0; it < 8; ++it) {
        int i = it*256 + tid, c = i >> 6, ww = i & 63;
        tl[ww][c] = f2bf(x[(((size_t)b*32 + c)*512 + h)*512 + w0 + ww]);
    }
    __syncthreads();
    const int ww = tid >> 2, c0 = (tid & 3) * 8;
    uint4 v;
    v.x = *(const uint*)&tl[ww][c0+0];
    v.y = *(const uint*)&tl[ww][c0+2];
    v.z = *(const uint*)&tl[ww][c0+4];
    v.w = *(const uint*)&tl[ww][c0+6];
    *(uint4*)(xt + ((((size_t)b*512 + h)*512 + w0 + ww)*32 + c0)) = v;
}

// ---------------- conv 3x3 via bf16 MFMA, fused bias + BN1 stats ----------------
__global__ __launch_bounds__(256) void k_conv_mfma(
    const ushort* __restrict__ xt, const ushort* __restrict__ wtp,
    const float* __restrict__ bias, float* __restrict__ out, float* __restrict__ stats)
{
    __shared__ float sred[64];
    const int tid = threadIdx.x;
    const int wid = tid >> 6, lane = tid & 63;
    const int h = blockIdx.y*4 + wid;
    const int w0 = blockIdx.x*64;
    const int b = blockIdx.z;

    short8 wa[9][2];
    #pragma unroll
    for (int tap = 0; tap < 9; ++tap)
        #pragma unroll
        for (int m = 0; m < 2; ++m)
            wa[tap][m] = *reinterpret_cast<const short8*>(wtp + ((tap*2 + m)*64 + lane)*8);

    f32x4 acc[2][4];
    #pragma unroll
    for (int m = 0; m < 2; ++m)
        #pragma unroll
        for (int n = 0; n < 4; ++n)
            acc[m][n] = (f32x4){0.f, 0.f, 0.f, 0.f};

    const int c0 = ((lane >> 4) & 3) * 8;
    const int pw = w0 + (lane & 15);
    const size_t ibase = (size_t)b * 512 * 512;

    #pragma unroll
    for (int dy = -1; dy <= 1; ++dy) {
        const int hh = h + dy;
        const bool hok = (unsigned)hh < 512u;
        #pragma unroll
        for (int dx = -1; dx <= 1; ++dx) {
            const int tap = (dy+1)*3 + (dx+1);
            short8 bfr[4];
            #pragma unroll
            for (int n = 0; n < 4; ++n) {
                const int ww = pw + n*16 + dx;
                short8 v = {0,0,0,0,0,0,0,0};
                if (hok && (unsigned)ww < 512u)
                    v = *reinterpret_cast<const short8*>(xt + ((ibase + (size_t)hh*512 + ww)*32 + c0));
                bfr[n] = v;
            }
            #pragma unroll
            for (int m = 0; m < 2; ++m)
                #pragma unroll
                for (int n = 0; n < 4; ++n)
                    acc[m][n] = __builtin_amdgcn_mfma_f32_16x16x32_bf16(wa[tap][m], bfr[n], acc[m][n], 0, 0, 0);
        }
    }

    if (tid < 64) sred[tid] = 0.f;
    __syncthreads();

    float bv[2][4];
    #pragma unroll
    for (int m = 0; m < 2; ++m)
        #pragma unroll
        for (int r = 0; r < 4; ++r)
            bv[m][r] = bias[m*16 + ((lane>>4)&3)*4 + r];

    float s8[8], q8[8];
    #pragma unroll
    for (int i = 0; i < 8; ++i) { s8[i] = 0.f; q8[i] = 0.f; }

    #pragma unroll
    for (int m = 0; m < 2; ++m) {
        #pragma unroll
        for (int n = 0; n < 4; ++n) {
            #pragma unroll
            for (int r = 0; r < 4; ++r) {
                const int co = m*16 + ((lane>>4)&3)*4 + r;
                const int ww = w0 + n*16 + (lane & 15);
                float val = acc[m][n][r] + bv[m][r];
                out[(((size_t)b*32 + co)*512 + h)*512 + ww] = val;
                s8[m*4+r] += val;
                q8[m*4+r] += val*val;
            }
        }
    }
    #pragma unroll
    for (int i = 0; i < 8; ++i) {
        #pragma unroll
        for (int off = 1; off < 16; off <<= 1) {
            s8[i] += __shfl_xor(s8[i], off, 64);
            q8[i] += __shfl_xor(q8[i], off, 64);
        }
    }
    if ((lane & 15) == 0) {
        #pragma unroll
        for (int m = 0; m < 2; ++m)
            #pragma unroll
            for (int r = 0; r < 4; ++r) {
                const int co = m*16 + ((lane>>4)&3)*4 + r;
                atomicAdd(&sred[co], s8[m*4+r]);
                atomicAdd(&sred[32+co], q8[m*4+r]);
            }
    }
    __syncthreads();
    if (tid < 64) {
        int bin = (blockIdx.y*8 + blockIdx.x + blockIdx.z) & 63;
        atomicAdd(&stats[bin*64 + tid], sred[tid]);
    }
}

__global__ void k_finalize(const float* __restrict__ stats, int nbins, const float* __restrict__ g,
                           const float* __restrict__ bta, float* __restrict__ bnp)
{
    int c = threadIdx.x;
    if (c < 32) {
        float s = 0.f, q = 0.f;
        for (int i = 0; i < nbins; ++i) { s += stats[i*64 + c]; q += stats[i*64 + 32 + c]; }
        const float inv_n = 1.f/1048576.f;
        float mean = s * inv_n;
        float var  = q * inv_n - mean*mean;
        float sc = g[c] * rsqrtf(var + 1e-5f);
        bnp[c] = sc;
        bnp[32+c] = bta[c] - mean*sc;
    }
}

// ---------------- row rfft (W axis), fused BN1+ReLU, transposed write ----------------
__global__ __launch_bounds__(512) void k_rowfft_fwd(
    const float* __restrict__ cvo, const float* __restrict__ bnp,
    float2* __restrict__ spec)
{
    __shared__ float2 tw[512];
    __shared__ float2 d[8*576];
    const int tid = threadIdx.x;
    const int h0 = blockIdx.x * 8;
    const int bc = blockIdx.y;
    const int c = bc & 31;
    fill_tw(tw, tid, 512);
    const float s1 = bnp[c], t1 = bnp[32+c];
    #pragma unroll
    for (int r = 0; r < 8; ++r) {
        float v = cvo[(bc*512 + h0 + r)*512 + tid];
        float y = fmaxf(fmaf(v, s1, t1), 0.f);
        d[r*576 + LPAD(drev(tid))] = make_float2(y, 0.f);
    }
    fft512_r8<8,512,false>(d, tw, tid);
    for (int i = tid; i < 8*WF; i += 512) {
        int ho = i & 7, w = i >> 3;
        spec[(bc*WF + w)*512 + h0 + ho] = d[ho*576 + LPAD(w)];
    }
}

// ---------------- col FFT (H) + MLP/gate + inverse col FFT, in place ----------------
__global__ __launch_bounds__(256) void k_colfft(float2* __restrict__ spec,
    const float* __restrict__ w1, const float* __restrict__ b1,
    const float* __restrict__ w2, const float* __restrict__ b2)
{
    __shared__ float2 tw[512];
    __shared__ float2 d[4*576];
    __shared__ float wl[80];
    const int tid = threadIdx.x;
    const int w = blockIdx.x;
    const int k = blockIdx.y;
    const int b = blockIdx.z;
    fill_tw(tw, tid, 256);
    if (tid < 16) {
        wl[tid]      = w1[k*16 + tid];
        wl[16 + tid] = w1[128 + k*16 + tid];
        wl[32 + tid] = w2[k*16 + tid];
        wl[48 + tid] = w2[128 + k*16 + tid];
    } else if (tid < 20) {
        int o = tid - 16;
        wl[64 + o] = b1[k*4 + o];
        wl[68 + o] = b1[32 + k*4 + o];
        wl[72 + o] = b2[k*4 + o];
        wl[76 + o] = b2[32 + k*4 + o];
    }
    const int base0 = ((b*32 + k*4)*WF + w) * 512;
    #pragma unroll
    for (int cc = 0; cc < 4; ++cc) {
        float4 v = ((const float4*)(spec + base0 + cc*(WF*512)))[tid];
        d[cc*576 + LPAD(drev(2*tid))]   = make_float2(v.x, v.y);
        d[cc*576 + LPAD(drev(2*tid+1))] = make_float2(v.z, v.w);
    }
    fft512_r8<4,256,false>(d, tw, tid);
    float zr[2][4], zi[2][4];
    #pragma unroll
    for (int rep = 0; rep < 2; ++rep) {
        const int ph = LPAD(rep*256 + tid);
        float xr[4], xi[4];
        #pragma unroll
        for (int i = 0; i < 4; ++i) {
            float2 v = d[i*576 + ph];
            xr[i] = v.x * (1.f/512.f);
            xi[i] = v.y * (1.f/512.f);
        }
        float o1r[4], o1i[4];
        #pragma unroll
        for (int o = 0; o < 4; ++o) {
            float sr = wl[64+o], si = wl[68+o];
            #pragma unroll
            for (int i = 0; i < 4; ++i) {
                float wr = wl[i*4+o], wi = wl[16 + i*4+o];
                sr += xr[i]*wr - xi[i]*wi;
                si += xi[i]*wr + xr[i]*wi;
            }
            o1r[o] = fmaxf(sr, 0.f);
            o1i[o] = fmaxf(si, 0.f);
        }
        #pragma unroll
        for (int o = 0; o < 4; ++o) {
            float sr = wl[72+o], si = wl[76+o];
            #pragma unroll
            for (int i = 0; i < 4; ++i) {
                float wr = wl[32 + i*4+o], wi = wl[48 + i*4+o];
                sr += o1r[i]*wr - o1i[i]*wi;
                si += o1i[i]*wr + o1r[i]*wi;
            }
            sr = (sr > LAM) ? sr - LAM : ((sr < -LAM) ? sr + LAM : 0.f);
            si = (si > LAM) ? si - LAM : ((si < -LAM) ? si + LAM : 0.f);
            zr[rep][o] = sr*xr[o] - si*xi[o];
            zi[rep][o] = sr*xi[o] + si*xr[o];
        }
    }
    __syncthreads();
    #pragma unroll
    for (int rep = 0; rep < 2; ++rep) {
        const int hb = LPAD(drev(rep*256 + tid));
        #pragma unroll
        for (int cc = 0; cc < 4; ++cc)
            d[cc*576 + hb] = make_float2(zr[rep][cc], zi[rep][cc]);
    }
    fft512_r8<4,256,true>(d, tw, tid);
    #pragma unroll
    for (int cc = 0; cc < 4; ++cc) {
        float2 a  = d[cc*576 + LPAD(2*tid)];
        float2 b2v = d[cc*576 + LPAD(2*tid+1)];
        ((float4*)(spec + base0 + cc*(WF*512)))[tid] = make_float4(a.x, a.y, b2v.x, b2v.y);
    }
}

// ---------------- row irfft (W axis) + residual + BN2 stats ----------------
__global__ __launch_bounds__(512) void k_rowfft_inv(
    const float2* __restrict__ spec, const float* __restrict__ cvo,
    const float* __restrict__ bnp, float* __restrict__ fo, float* __restrict__ stats2)
{
    __shared__ float2 tw[512];
    __shared__ float2 d[8*576];
    __shared__ float2 red[8];
    const int tid = threadIdx.x;
    const int h0 = blockIdx.x * 8;
    const int bc = blockIdx.y;
    const int c = bc & 31;
    fill_tw(tw, tid, 512);
    for (int i = tid; i < 8*WF; i += 512) {
        int ho = i & 7, w = i >> 3;
        float2 v = spec[(bc*WF + w)*512 + h0 + ho];
        d[ho*576 + LPAD(drev(w))] = v;
        if ((unsigned)(w - 1) < 255u)
            d[ho*576 + LPAD(drev(512 - w))] = make_float2(v.x, -v.y);
    }
    fft512_r8<8,512,true>(d, tw, tid);
    const float s1 = bnp[c], t1 = bnp[32+c];
    float ls = 0.f, lsq = 0.f;
    #pragma unroll
    for (int r = 0; r < 8; ++r) {
        int gi = (bc*512 + h0 + r)*512 + tid;
        float cv = cvo[gi];
        float yv = fmaxf(fmaf(cv, s1, t1), 0.f);
        float val = fmaf(d[r*576 + LPAD(tid)].x, (1.f/512.f), yv);
        fo[gi] = val;
        ls += val; lsq += val*val;
    }
    #pragma unroll
    for (int off = 32; off; off >>= 1) { ls += __shfl_down(ls, off, 64); lsq += __shfl_down(lsq, off, 64); }
    if ((tid & 63) == 0) red[tid >> 6] = make_float2(ls, lsq);
    __syncthreads();
    if (tid == 0) {
        float a = 0.f, bb = 0.f;
        #pragma unroll
        for (int i = 0; i < 8; ++i){ a += red[i].x; bb += red[i].y; }
        atomicAdd(&stats2[c], a);
        atomicAdd(&stats2[32+c], bb);
    }
}

// ---------------- final: out = relu(y + bn2(fo)) ----------------
__global__ __launch_bounds__(256) void k_final(const float* __restrict__ cvo,
    const float* __restrict__ bnp1, const float* __restrict__ bnp2, float* __restrict__ out)
{
    const int n4 = 8388608;
    for (int i = blockIdx.x*256 + threadIdx.x; i < n4; i += gridDim.x*256) {
        int c = (i >> 16) & 31;
        float s1 = bnp1[c], t1 = bnp1[32+c], s2 = bnp2[c], t2 = bnp2[32+c];
        float4 cv = ((const float4*)cvo)[i];
        float4 fv = ((float4*)out)[i];
        float4 r;
        r.x = fmaxf(fmaxf(fmaf(cv.x,s1,t1),0.f) + fmaf(fv.x,s2,t2), 0.f);
        r.y = fmaxf(fmaxf(fmaf(cv.y,s1,t1),0.f) + fmaf(fv.y,s2,t2), 0.f);
        r.z = fmaxf(fmaxf(fmaf(cv.z,s1,t1),0.f) + fmaf(fv.z,s2,t2), 0.f);
        r.w = fmaxf(fmaxf(fmaf(cv.w,s1,t1),0.f) + fmaf(fv.w,s2,t2), 0.f);
        ((float4*)out)[i] = r;
    }
}

extern "C" void kernel_launch(void* const* d_in, const int* in_sizes, int n_in,
                              void* d_out, int out_size, void* d_ws, size_t ws_size,
                              hipStream_t stream)
{
    const float* x      = (const float*)d_in[0];
    const float* conv_w = (const float*)d_in[1];
    const float* conv_b = (const float*)d_in[2];
    const float* bn1g   = (const float*)d_in[3];
    const float* bn1b   = (const float*)d_in[4];
    const float* w1     = (const float*)d_in[5];
    const float* b1     = (const float*)d_in[6];
    const float* w2     = (const float*)d_in[7];
    const float* b2     = (const float*)d_in[8];
    const float* bn2g   = (const float*)d_in[9];
    const float* bn2b   = (const float*)d_in[10];
    float* out = (float*)d_out;

    char* ws = (char*)d_ws;
    float2* spec  = (float2*)ws;                          // 134,742,016 B
    ushort* xt    = (ushort*)ws;                          // 67,108,864 B (aliases spec; dead before spec written)
    float*  cvo   = (float*)(ws + 134742016);             // 134,217,728 B
    ushort* wtp   = (ushort*)(ws + 134742016 + 134217728);// 18,432 B
    float*  stats = (float*)(ws + 134742016 + 134217728 + 18432);
    float* stats1 = stats;            // 4096 floats (64 bins x 64)
    float* stats2 = stats + 4096;     // 64 floats
    float* bnp1   = stats + 4160;     // 64 floats
    float* bnp2   = stats + 4224;     // 64 floats

    hipMemsetAsync(stats, 0, 4160*sizeof(float), stream);
    k_wprep<<<36, 256, 0, stream>>>(conv_w, wtp);
    k_transpose<<<dim3(8,512,4), 256, 0, stream>>>(x, xt);
    k_conv_mfma<<<dim3(8,128,4), 256, 0, stream>>>(xt, wtp, conv_b, cvo, stats1);
    k_finalize<<<1, 64, 0, stream>>>(stats1, 64, bn1g, bn1b, bnp1);
    k_rowfft_fwd<<<dim3(64,128), 512, 0, stream>>>(cvo, bnp1, spec);
    k_colfft<<<dim3(257,8,4), 256, 0, stream>>>(spec, w1, b1, w2, b2);
    k_rowfft_inv<<<dim3(64,128), 512, 0, stream>>>(spec, cvo, bnp1, out, stats2);
    k_finalize<<<1, 64, 0, stream>>>(stats2, 1, bn2g, bn2b, bnp2);
    k_final<<<2048, 256, 0, stream>>>(cvo, bnp1, bnp2, out);
}